// Round 6
// baseline (911.664 us; speedup 1.0000x reference)
//
#include <hip/hip_runtime.h>
#include <hip/hip_bf16.h>
#include <hip/hip_fp16.h>
#include <math.h>

// DAGNN propagation, CSR-gather, fp16 state, wide gather (8 edges/wave-instr),
// bucketed two-phase CSR build (kills 16x scatter write amplification),
// grid-stride persistent hop waves (cross-node pipelining).

#define DIM 64
#define BUCKET_SHIFT 6            // 64 nodes per bucket
#define HOP_BLOCKS 1536           // 6 blocks/CU, 24 waves/CU

// ---- zero int region ----
__global__ void zero_int_kernel(int* __restrict__ p, int n) {
    int i = blockIdx.x * blockDim.x + threadIdx.x;
    if (i < n) p[i] = 0;
}

// ---- in-degree (int atomics) ----
__global__ void degree_kernel(const int* __restrict__ dst, int* __restrict__ deg, int E) {
    int e = blockIdx.x * blockDim.x + threadIdx.x;
    if (e < E) atomicAdd(&deg[dst[e]], 1);
}

// ---- norm = deg^-0.5 ----
__global__ void norm_kernel(const int* __restrict__ deg, float* __restrict__ norm, int N) {
    int i = blockIdx.x * blockDim.x + threadIdx.x;
    if (i < N) norm[i] = rsqrtf((float)deg[i]);
}

// ---- exclusive scan, stage 1: per-1024-chunk scan + chunk totals ----
__global__ void scan1_kernel(const int* __restrict__ deg, int* __restrict__ rp,
                             int* __restrict__ chunk_sums, int N) {
    __shared__ int lds[256];
    int t = threadIdx.x;
    int base = blockIdx.x * 1024 + t * 4;
    int v0 = (base + 0 < N) ? deg[base + 0] : 0;
    int v1 = (base + 1 < N) ? deg[base + 1] : 0;
    int v2 = (base + 2 < N) ? deg[base + 2] : 0;
    int v3 = (base + 3 < N) ? deg[base + 3] : 0;
    int tsum = v0 + v1 + v2 + v3;
    lds[t] = tsum;
    __syncthreads();
    for (int off = 1; off < 256; off <<= 1) {
        int x = (t >= off) ? lds[t - off] : 0;
        __syncthreads();
        lds[t] += x;
        __syncthreads();
    }
    int excl = lds[t] - tsum;
    if (t == 255) chunk_sums[blockIdx.x] = lds[255];
    int p = excl;
    if (base + 0 < N) rp[base + 0] = p; p += v0;
    if (base + 1 < N) rp[base + 1] = p; p += v1;
    if (base + 2 < N) rp[base + 2] = p; p += v2;
    if (base + 3 < N) rp[base + 3] = p;
}

// ---- exclusive scan, stage 2 (single block, B <= 256) ----
__global__ void scan2_kernel(int* __restrict__ chunk_sums, int B) {
    __shared__ int lds[256];
    int t = threadIdx.x;
    int v = (t < B) ? chunk_sums[t] : 0;
    lds[t] = v;
    __syncthreads();
    for (int off = 1; off < 256; off <<= 1) {
        int x = (t >= off) ? lds[t - off] : 0;
        __syncthreads();
        lds[t] += x;
        __syncthreads();
    }
    if (t < B) chunk_sums[t] = lds[t] - v;  // exclusive
}

// ---- scan stage 3: finalize rp; init node cursor; rp[N]=E ----
__global__ void scan3_kernel(int* __restrict__ rp, const int* __restrict__ chunk_sums,
                             int* __restrict__ cursor, int N, int E) {
    int i = blockIdx.x * blockDim.x + threadIdx.x;
    if (i < N) {
        int val = rp[i] + chunk_sums[i >> 10];
        rp[i] = val;
        cursor[i] = val;
    }
    if (i == 0) rp[N] = E;
}

// ---- bucket cursor init: bc[b] = rp[min(64b, N)] ----
__global__ void bc_init_kernel(const int* __restrict__ rp, int* __restrict__ bc,
                               int NB, int N) {
    int b = blockIdx.x * blockDim.x + threadIdx.x;
    if (b < NB) {
        int node = b << BUCKET_SHIFT;
        if (node > N) node = N;
        bc[b] = rp[node];
    }
}

// ---- phase A: scatter (src,dst) pairs into coarse bucket regions ----
// Active write working set = NB bucket tails (~200KB) -> L2-resident -> ~1x amp.
__global__ void phaseA_kernel(const int* __restrict__ src, const int* __restrict__ dst,
                              int* __restrict__ bc, int2* __restrict__ pairs, int E) {
    int e = blockIdx.x * blockDim.x + threadIdx.x;
    if (e < E) {
        int d = dst[e];
        int pos = atomicAdd(&bc[d >> BUCKET_SHIFT], 1);
        pairs[pos] = make_int2(src[e], d);
    }
}

// ---- phase B: within-bucket fill; cursor lines + col window are L2-hot ----
__global__ void phaseB_kernel(const int2* __restrict__ pairs, const int* __restrict__ rp,
                              int* __restrict__ cursor, int* __restrict__ col,
                              int NB, int N) {
    int b = blockIdx.x;
    int lo_node = b << BUCKET_SHIFT;
    int hi_node = lo_node + (1 << BUCKET_SHIFT);
    if (hi_node > N) hi_node = N;
    int beg = rp[lo_node];
    int end = rp[hi_node];
    for (int j = beg + threadIdx.x; j < end; j += blockDim.x) {
        int2 p = pairs[j];
        int pos = atomicAdd(&cursor[p.y], 1);
        col[pos] = p.x;
    }
}

// ---- init: out = sigmoid(feats.s)*feats ; w0 = half(feats*norm) ----
__global__ void init_kernel(const float* __restrict__ feats,
                            const float* __restrict__ norm,
                            const float* __restrict__ s,
                            float* __restrict__ out,
                            __half* __restrict__ w, int N) {
    int n = blockIdx.x * (blockDim.x >> 6) + (threadIdx.x >> 6);
    int lane = threadIdx.x & 63;
    if (n >= N) return;
    size_t idx = ((size_t)n << 6) + lane;
    float v = feats[idx];
    float p = v * s[lane];
    #pragma unroll
    for (int off = 32; off; off >>= 1) p += __shfl_xor(p, off, 64);
    float gate = 1.0f / (1.0f + expf(-p));
    out[idx] = gate * v;
    w[idx] = __float2half(v * norm[n]);
}

// ---- fused hop: wide CSR gather, grid-stride persistent waves ----
__global__ void gather_hop_kernel(const __half* __restrict__ w,
                                  const int* __restrict__ rp,
                                  const int* __restrict__ col,
                                  const float* __restrict__ norm,
                                  const float* __restrict__ s,
                                  float* __restrict__ out,
                                  __half* __restrict__ wnext,
                                  int N, int write_next) {
    int lane  = threadIdx.x & 63;
    int e_sub = lane >> 3;   // edge slot 0..7
    int c     = lane & 7;    // feature chunk 0..7 (8 fp16 = 16B)
    int wid = blockIdx.x * (blockDim.x >> 6) + (threadIdx.x >> 6);
    int W   = gridDim.x * (blockDim.x >> 6);

    // s is loop-invariant: hoist
    float4 sa = *(const float4*)(s + (c << 3));
    float4 sb = *(const float4*)(s + (c << 3) + 4);

    for (int n = wid; n < N; n += W) {
        int beg = rp[n];
        int end = rp[n + 1];

        float acc[8];
        #pragma unroll
        for (int i = 0; i < 8; ++i) acc[i] = 0.0f;

        for (int j = beg + e_sub; j < end; j += 8) {
            int cc = col[j];
            float4 raw = *(const float4*)(w + ((size_t)cc << 6) + (c << 3));
            const __half2* h2 = (const __half2*)&raw;
            float2 f0 = __half22float2(h2[0]);
            float2 f1 = __half22float2(h2[1]);
            float2 f2 = __half22float2(h2[2]);
            float2 f3 = __half22float2(h2[3]);
            acc[0] += f0.x; acc[1] += f0.y;
            acc[2] += f1.x; acc[3] += f1.y;
            acc[4] += f2.x; acc[5] += f2.y;
            acc[6] += f3.x; acc[7] += f3.y;
        }

        // fold edge slots (lane bits 3..5)
        #pragma unroll
        for (int off = 8; off < 64; off <<= 1) {
            #pragma unroll
            for (int i = 0; i < 8; ++i) acc[i] += __shfl_xor(acc[i], off, 64);
        }

        float nm = norm[n];
        float v[8];
        #pragma unroll
        for (int i = 0; i < 8; ++i) v[i] = acc[i] * nm;   // h_{k+1}[n, 8c..8c+7]

        // gate: dot(v, s) — reduce over c (lane bits 0..2)
        float p = v[0] * sa.x + v[1] * sa.y + v[2] * sa.z + v[3] * sa.w
                + v[4] * sb.x + v[5] * sb.y + v[6] * sb.z + v[7] * sb.w;
        #pragma unroll
        for (int off = 1; off < 8; off <<= 1) p += __shfl_xor(p, off, 64);
        float gate = 1.0f / (1.0f + expf(-p));

        size_t base = ((size_t)n << 6) + (c << 3);
        if (e_sub == 0) {
            float4* o = (float4*)(out + base);
            float4 o0 = o[0], o1 = o[1];
            o0.x += gate * v[0]; o0.y += gate * v[1];
            o0.z += gate * v[2]; o0.w += gate * v[3];
            o1.x += gate * v[4]; o1.y += gate * v[5];
            o1.z += gate * v[6]; o1.w += gate * v[7];
            o[0] = o0; o[1] = o1;
        } else if (e_sub == 1 && write_next) {
            __half2 hv[4];
            hv[0] = __floats2half2_rn(v[0] * nm, v[1] * nm);
            hv[1] = __floats2half2_rn(v[2] * nm, v[3] * nm);
            hv[2] = __floats2half2_rn(v[4] * nm, v[5] * nm);
            hv[3] = __floats2half2_rn(v[6] * nm, v[7] * nm);
            *(float4*)(wnext + base) = *(const float4*)hv;
        }
    }
}

extern "C" void kernel_launch(void* const* d_in, const int* in_sizes, int n_in,
                              void* d_out, int out_size, void* d_ws, size_t ws_size,
                              hipStream_t stream) {
    const float* feats = (const float*)d_in[0];
    const float* s     = (const float*)d_in[1];
    const int*   src   = (const int*)d_in[2];
    const int*   dst   = (const int*)d_in[3];
    float* out = (float*)d_out;

    const int N = in_sizes[0] / DIM;
    const int E = in_sizes[2];
    const int NB = (N + (1 << BUCKET_SHIFT) - 1) >> BUCKET_SHIFT;  // 1563

    // workspace: [norm:N f][wA:N*64 h][wB:N*64 h][rp:N+1][deg:N][cursor:N][col:E][chunk:256][bc:NB][pairs:E int2]
    float*  norm   = (float*)d_ws;
    __half* wA     = (__half*)(norm + N);
    __half* wB     = wA + (size_t)N * DIM;
    int*    rp     = (int*)(wB + (size_t)N * DIM);
    int*    deg    = rp + (N + 1);
    int*    cursor = deg + N;
    int*    col    = cursor + N;
    int*    chunk  = col + E;
    int*    bc     = chunk + 256;
    size_t  off    = (size_t)((char*)(bc + NB) - (char*)d_ws);
    off = (off + 7) & ~(size_t)7;
    int2*   pairs  = (int2*)((char*)d_ws + off);

    const int BLK = 256;
    const int wavesPerBlk = BLK / 64;
    const int chunks = (N + 1023) / 1024;   // 98 (must be <= 256)

    zero_int_kernel<<<(N + BLK - 1) / BLK, BLK, 0, stream>>>(deg, N);
    degree_kernel<<<(E + BLK - 1) / BLK, BLK, 0, stream>>>(dst, deg, E);
    norm_kernel<<<(N + BLK - 1) / BLK, BLK, 0, stream>>>(deg, norm, N);

    // CSR build: scan -> bucket scatter -> local fill
    scan1_kernel<<<chunks, 256, 0, stream>>>(deg, rp, chunk, N);
    scan2_kernel<<<1, 256, 0, stream>>>(chunk, chunks);
    scan3_kernel<<<(N + BLK - 1) / BLK, BLK, 0, stream>>>(rp, chunk, cursor, N, E);
    bc_init_kernel<<<(NB + BLK - 1) / BLK, BLK, 0, stream>>>(rp, bc, NB, N);
    phaseA_kernel<<<(E + BLK - 1) / BLK, BLK, 0, stream>>>(src, dst, bc, pairs, E);
    phaseB_kernel<<<NB, BLK, 0, stream>>>(pairs, rp, cursor, col, NB, N);

    // k = 0 readout + initial pre-scaled state
    int nodeBlocks = (N + wavesPerBlk - 1) / wavesPerBlk;
    init_kernel<<<nodeBlocks, BLK, 0, stream>>>(feats, norm, s, out, wA, N);

    const int K = 10;
    __half* cur = wA;
    __half* nxt = wB;
    for (int k = 0; k < K; ++k) {
        int write_next = (k < K - 1) ? 1 : 0;
        gather_hop_kernel<<<HOP_BLOCKS, BLK, 0, stream>>>(cur, rp, col, norm, s,
                                                          out, nxt, N, write_next);
        __half* t = cur; cur = nxt; nxt = t;
    }
}

// Round 7
// 716.823 us; speedup vs baseline: 1.2718x; 1.2718x over previous
//
#include <hip/hip_runtime.h>
#include <hip/hip_bf16.h>
#include <hip/hip_fp16.h>
#include <math.h>

// DAGNN propagation, CSR-gather, fp16 state, wide gather (8 edges/wave-instr).
// Round 7: hops store ALL K+1 state buffers (no out RMW in the hop loop);
// one final readout sweep computes out = sum_k sigmoid(h_k.s)*h_k.
// Falls back to the round-5 fused-RMW path if ws_size is too small.

#define DIM 64

// ---- zero int region ----
__global__ void zero_int_kernel(int* __restrict__ p, int n) {
    int i = blockIdx.x * blockDim.x + threadIdx.x;
    if (i < n) p[i] = 0;
}

// ---- in-degree (int atomics) ----
__global__ void degree_kernel(const int* __restrict__ dst, int* __restrict__ deg, int E) {
    int e = blockIdx.x * blockDim.x + threadIdx.x;
    if (e < E) atomicAdd(&deg[dst[e]], 1);
}

// ---- norm = deg^-0.5 ----
__global__ void norm_kernel(const int* __restrict__ deg, float* __restrict__ norm, int N) {
    int i = blockIdx.x * blockDim.x + threadIdx.x;
    if (i < N) norm[i] = rsqrtf((float)deg[i]);
}

// ---- exclusive scan, stage 1: per-1024-chunk scan + chunk totals ----
__global__ void scan1_kernel(const int* __restrict__ deg, int* __restrict__ rp,
                             int* __restrict__ chunk_sums, int N) {
    __shared__ int lds[256];
    int t = threadIdx.x;
    int base = blockIdx.x * 1024 + t * 4;
    int v0 = (base + 0 < N) ? deg[base + 0] : 0;
    int v1 = (base + 1 < N) ? deg[base + 1] : 0;
    int v2 = (base + 2 < N) ? deg[base + 2] : 0;
    int v3 = (base + 3 < N) ? deg[base + 3] : 0;
    int tsum = v0 + v1 + v2 + v3;
    lds[t] = tsum;
    __syncthreads();
    for (int off = 1; off < 256; off <<= 1) {
        int x = (t >= off) ? lds[t - off] : 0;
        __syncthreads();
        lds[t] += x;
        __syncthreads();
    }
    int excl = lds[t] - tsum;
    if (t == 255) chunk_sums[blockIdx.x] = lds[255];
    int p = excl;
    if (base + 0 < N) rp[base + 0] = p; p += v0;
    if (base + 1 < N) rp[base + 1] = p; p += v1;
    if (base + 2 < N) rp[base + 2] = p; p += v2;
    if (base + 3 < N) rp[base + 3] = p;
}

// ---- exclusive scan, stage 2 (single block, B <= 256) ----
__global__ void scan2_kernel(int* __restrict__ chunk_sums, int B) {
    __shared__ int lds[256];
    int t = threadIdx.x;
    int v = (t < B) ? chunk_sums[t] : 0;
    lds[t] = v;
    __syncthreads();
    for (int off = 1; off < 256; off <<= 1) {
        int x = (t >= off) ? lds[t - off] : 0;
        __syncthreads();
        lds[t] += x;
        __syncthreads();
    }
    if (t < B) chunk_sums[t] = lds[t] - v;  // exclusive
}

// ---- scan stage 3: finalize rp; init cursor; rp[N]=E ----
__global__ void scan3_kernel(int* __restrict__ rp, const int* __restrict__ chunk_sums,
                             int* __restrict__ cursor, int N, int E) {
    int i = blockIdx.x * blockDim.x + threadIdx.x;
    if (i < N) {
        int val = rp[i] + chunk_sums[i >> 10];
        rp[i] = val;
        cursor[i] = val;
    }
    if (i == 0) rp[N] = E;
}

// ---- CSR fill: col[pos] = src[e] ----
__global__ void fill_kernel(const int* __restrict__ src, const int* __restrict__ dst,
                            int* __restrict__ cursor, int* __restrict__ col, int E) {
    int e = blockIdx.x * blockDim.x + threadIdx.x;
    if (e < E) {
        int d = dst[e];
        int pos = atomicAdd(&cursor[d], 1);
        col[pos] = src[e];
    }
}

// ---- init (full path): w0 = half(feats*norm) only ----
__global__ void init_w0_kernel(const float* __restrict__ feats,
                               const float* __restrict__ norm,
                               __half* __restrict__ w, int N) {
    int n = blockIdx.x * (blockDim.x >> 6) + (threadIdx.x >> 6);
    int lane = threadIdx.x & 63;
    if (n >= N) return;
    size_t idx = ((size_t)n << 6) + lane;
    w[idx] = __float2half(feats[idx] * norm[n]);
}

// ---- init (fallback path): out = sigmoid(feats.s)*feats ; w0 = half(feats*norm) ----
__global__ void init_kernel(const float* __restrict__ feats,
                            const float* __restrict__ norm,
                            const float* __restrict__ s,
                            float* __restrict__ out,
                            __half* __restrict__ w, int N) {
    int n = blockIdx.x * (blockDim.x >> 6) + (threadIdx.x >> 6);
    int lane = threadIdx.x & 63;
    if (n >= N) return;
    size_t idx = ((size_t)n << 6) + lane;
    float v = feats[idx];
    float p = v * s[lane];
    #pragma unroll
    for (int off = 32; off; off >>= 1) p += __shfl_xor(p, off, 64);
    float gate = 1.0f / (1.0f + expf(-p));
    out[idx] = gate * v;
    w[idx] = __float2half(v * norm[n]);
}

// ---- hop (full path): wide gather + next-state write, nothing else ----
__global__ void gather_hop_store_kernel(const __half* __restrict__ w,
                                        const int* __restrict__ rp,
                                        const int* __restrict__ col,
                                        const float* __restrict__ norm,
                                        __half* __restrict__ wnext, int N) {
    int n = blockIdx.x * (blockDim.x >> 6) + (threadIdx.x >> 6);
    if (n >= N) return;
    int lane  = threadIdx.x & 63;
    int e_sub = lane >> 3;   // edge slot 0..7
    int c     = lane & 7;    // feature chunk 0..7 (8 fp16 = 16B)

    int beg = rp[n];
    int end = rp[n + 1];

    float acc[8];
    #pragma unroll
    for (int i = 0; i < 8; ++i) acc[i] = 0.0f;

    for (int j = beg + e_sub; j < end; j += 8) {
        int cc = col[j];
        float4 raw = *(const float4*)(w + ((size_t)cc << 6) + (c << 3));
        const __half2* h2 = (const __half2*)&raw;
        float2 f0 = __half22float2(h2[0]);
        float2 f1 = __half22float2(h2[1]);
        float2 f2 = __half22float2(h2[2]);
        float2 f3 = __half22float2(h2[3]);
        acc[0] += f0.x; acc[1] += f0.y;
        acc[2] += f1.x; acc[3] += f1.y;
        acc[4] += f2.x; acc[5] += f2.y;
        acc[6] += f3.x; acc[7] += f3.y;
    }

    // fold edge slots (lane bits 3..5) — all lanes end with full sums
    #pragma unroll
    for (int off = 8; off < 64; off <<= 1) {
        #pragma unroll
        for (int i = 0; i < 8; ++i) acc[i] += __shfl_xor(acc[i], off, 64);
    }

    if (e_sub == 0) {
        float nm = norm[n];
        float n2 = nm * nm;
        __half2 hv[4];
        hv[0] = __floats2half2_rn(acc[0] * n2, acc[1] * n2);
        hv[1] = __floats2half2_rn(acc[2] * n2, acc[3] * n2);
        hv[2] = __floats2half2_rn(acc[4] * n2, acc[5] * n2);
        hv[3] = __floats2half2_rn(acc[6] * n2, acc[7] * n2);
        *(float4*)(wnext + ((size_t)n << 6) + (c << 3)) = *(const float4*)hv;
    }
}

// ---- final readout (full path): out = sum_k sigmoid(h_k.s)*h_k, h_k = w_k/nm ----
__global__ void readout_kernel(const __half* __restrict__ wbase,  // w_0
                               const float* __restrict__ norm,
                               const float* __restrict__ s,
                               float* __restrict__ out,
                               int N, int nk, size_t kstride) {
    int n = blockIdx.x * (blockDim.x >> 6) + (threadIdx.x >> 6);
    if (n >= N) return;
    int lane = threadIdx.x & 63;
    size_t idx = ((size_t)n << 6) + lane;
    float inm = 1.0f / norm[n];   // = sqrt(deg)
    float sl = s[lane];
    float acc = 0.0f;
    for (int k = 0; k < nk; ++k) {
        float hk = __half2float(wbase[idx + (size_t)k * kstride]) * inm;
        float p = hk * sl;
        #pragma unroll
        for (int off = 32; off; off >>= 1) p += __shfl_xor(p, off, 64);
        float gate = 1.0f / (1.0f + expf(-p));
        acc += gate * hk;
    }
    out[idx] = acc;
}

// ---- hop (fallback path, round-5): gather + gate + out RMW + next-state ----
__global__ void gather_hop_kernel(const __half* __restrict__ w,
                                  const int* __restrict__ rp,
                                  const int* __restrict__ col,
                                  const float* __restrict__ norm,
                                  const float* __restrict__ s,
                                  float* __restrict__ out,
                                  __half* __restrict__ wnext,
                                  int N, int write_next) {
    int n = blockIdx.x * (blockDim.x >> 6) + (threadIdx.x >> 6);
    if (n >= N) return;
    int lane = threadIdx.x & 63;
    int e_sub = lane >> 3;
    int c     = lane & 7;

    int beg = rp[n];
    int end = rp[n + 1];

    float acc[8];
    #pragma unroll
    for (int i = 0; i < 8; ++i) acc[i] = 0.0f;

    for (int j = beg + e_sub; j < end; j += 8) {
        int cc = col[j];
        float4 raw = *(const float4*)(w + ((size_t)cc << 6) + (c << 3));
        const __half2* h2 = (const __half2*)&raw;
        float2 f0 = __half22float2(h2[0]);
        float2 f1 = __half22float2(h2[1]);
        float2 f2 = __half22float2(h2[2]);
        float2 f3 = __half22float2(h2[3]);
        acc[0] += f0.x; acc[1] += f0.y;
        acc[2] += f1.x; acc[3] += f1.y;
        acc[4] += f2.x; acc[5] += f2.y;
        acc[6] += f3.x; acc[7] += f3.y;
    }

    #pragma unroll
    for (int off = 8; off < 64; off <<= 1) {
        #pragma unroll
        for (int i = 0; i < 8; ++i) acc[i] += __shfl_xor(acc[i], off, 64);
    }

    float nm = norm[n];
    float v[8];
    #pragma unroll
    for (int i = 0; i < 8; ++i) v[i] = acc[i] * nm;

    float4 sa = *(const float4*)(s + (c << 3));
    float4 sb = *(const float4*)(s + (c << 3) + 4);
    float p = v[0] * sa.x + v[1] * sa.y + v[2] * sa.z + v[3] * sa.w
            + v[4] * sb.x + v[5] * sb.y + v[6] * sb.z + v[7] * sb.w;
    #pragma unroll
    for (int off = 1; off < 8; off <<= 1) p += __shfl_xor(p, off, 64);
    float gate = 1.0f / (1.0f + expf(-p));

    size_t base = ((size_t)n << 6) + (c << 3);
    if (e_sub == 0) {
        float4* o = (float4*)(out + base);
        float4 o0 = o[0], o1 = o[1];
        o0.x += gate * v[0]; o0.y += gate * v[1];
        o0.z += gate * v[2]; o0.w += gate * v[3];
        o1.x += gate * v[4]; o1.y += gate * v[5];
        o1.z += gate * v[6]; o1.w += gate * v[7];
        o[0] = o0; o[1] = o1;
    } else if (e_sub == 1 && write_next) {
        __half2 hv[4];
        hv[0] = __floats2half2_rn(v[0] * nm, v[1] * nm);
        hv[1] = __floats2half2_rn(v[2] * nm, v[3] * nm);
        hv[2] = __floats2half2_rn(v[4] * nm, v[5] * nm);
        hv[3] = __floats2half2_rn(v[6] * nm, v[7] * nm);
        *(float4*)(wnext + base) = *(const float4*)hv;
    }
}

extern "C" void kernel_launch(void* const* d_in, const int* in_sizes, int n_in,
                              void* d_out, int out_size, void* d_ws, size_t ws_size,
                              hipStream_t stream) {
    const float* feats = (const float*)d_in[0];
    const float* s     = (const float*)d_in[1];
    const int*   src   = (const int*)d_in[2];
    const int*   dst   = (const int*)d_in[3];
    float* out = (float*)d_out;

    const int N = in_sizes[0] / DIM;
    const int E = in_sizes[2];
    const int K = 10;

    const int BLK = 256;
    const int wavesPerBlk = BLK / 64;
    const int chunks = (N + 1023) / 1024;   // must be <= 256
    int nodeBlocks = (N + wavesPerBlk - 1) / wavesPerBlk;
    int intCount = (N + 1) + N + N + E + 256;   // rp, deg, cursor, col, chunk

    // full path needs: norm(4N) + (K+1) fp16 bufs (2*N*64 each) + ints
    size_t stateElems = (size_t)N * DIM;
    size_t need_full = (size_t)N * 4 + (size_t)(K + 1) * stateElems * 2
                     + (size_t)intCount * 4 + 64;
    int full = (ws_size >= need_full) ? 1 : 0;
    int nbuf = full ? (K + 1) : 2;

    float*  norm  = (float*)d_ws;
    __half* wbase = (__half*)(norm + N);
    int*    rp     = (int*)(wbase + (size_t)nbuf * stateElems);
    int*    deg    = rp + (N + 1);
    int*    cursor = deg + N;
    int*    col    = cursor + N;
    int*    chunk  = col + E;

    zero_int_kernel<<<(N + BLK - 1) / BLK, BLK, 0, stream>>>(deg, N);
    degree_kernel<<<(E + BLK - 1) / BLK, BLK, 0, stream>>>(dst, deg, E);
    norm_kernel<<<(N + BLK - 1) / BLK, BLK, 0, stream>>>(deg, norm, N);

    scan1_kernel<<<chunks, 256, 0, stream>>>(deg, rp, chunk, N);
    scan2_kernel<<<1, 256, 0, stream>>>(chunk, chunks);
    scan3_kernel<<<(N + BLK - 1) / BLK, BLK, 0, stream>>>(rp, chunk, cursor, N, E);
    fill_kernel<<<(E + BLK - 1) / BLK, BLK, 0, stream>>>(src, dst, cursor, col, E);

    if (full) {
        // --- round-7 path: store all K+1 states, readout at the end ---
        init_w0_kernel<<<nodeBlocks, BLK, 0, stream>>>(feats, norm, wbase, N);
        for (int k = 0; k < K; ++k) {
            const __half* cur = wbase + (size_t)k * stateElems;
            __half* nxt = wbase + (size_t)(k + 1) * stateElems;
            gather_hop_store_kernel<<<nodeBlocks, BLK, 0, stream>>>(cur, rp, col,
                                                                    norm, nxt, N);
        }
        readout_kernel<<<nodeBlocks, BLK, 0, stream>>>(wbase, norm, s, out,
                                                       N, K + 1, stateElems);
    } else {
        // --- fallback: round-5 fused path (ping-pong 2 buffers) ---
        __half* wA = wbase;
        __half* wB = wbase + stateElems;
        init_kernel<<<nodeBlocks, BLK, 0, stream>>>(feats, norm, s, out, wA, N);
        __half* cur = wA;
        __half* nxt = wB;
        for (int k = 0; k < K; ++k) {
            int write_next = (k < K - 1) ? 1 : 0;
            gather_hop_kernel<<<nodeBlocks, BLK, 0, stream>>>(cur, rp, col, norm, s,
                                                              out, nxt, N, write_next);
            __half* t = cur; cur = nxt; nxt = t;
        }
    }
}

// Round 9
// 639.231 us; speedup vs baseline: 1.4262x; 1.1214x over previous
//
#include <hip/hip_runtime.h>
#include <hip/hip_bf16.h>
#include <hip/hip_fp16.h>
#include <math.h>

// DAGNN propagation, CSR-gather, fp16 state, wide gather (8 edges/wave-instr).
// Round 9: round-8 structure with the ds_bpermute divergence bug fixed:
// the col-index __shfl now runs with ALL 64 lanes active (uniform trip count,
// masked accumulate) — reading from inactive lanes returns 0 on CDNA and
// silently dropped edges for deg in (8t, 9t].

#define DIM 64

// ---- zero int region ----
__global__ void zero_int_kernel(int* __restrict__ p, int n) {
    int i = blockIdx.x * blockDim.x + threadIdx.x;
    if (i < n) p[i] = 0;
}

// ---- in-degree (int atomics) ----
__global__ void degree_kernel(const int* __restrict__ dst, int* __restrict__ deg, int E) {
    int e = blockIdx.x * blockDim.x + threadIdx.x;
    if (e < E) atomicAdd(&deg[dst[e]], 1);
}

// ---- norm = deg^-0.5 ----
__global__ void norm_kernel(const int* __restrict__ deg, float* __restrict__ norm, int N) {
    int i = blockIdx.x * blockDim.x + threadIdx.x;
    if (i < N) norm[i] = rsqrtf((float)deg[i]);
}

// ---- exclusive scan, stage 1: per-1024-chunk scan + chunk totals ----
__global__ void scan1_kernel(const int* __restrict__ deg, int* __restrict__ rp,
                             int* __restrict__ chunk_sums, int N) {
    __shared__ int lds[256];
    int t = threadIdx.x;
    int base = blockIdx.x * 1024 + t * 4;
    int v0 = (base + 0 < N) ? deg[base + 0] : 0;
    int v1 = (base + 1 < N) ? deg[base + 1] : 0;
    int v2 = (base + 2 < N) ? deg[base + 2] : 0;
    int v3 = (base + 3 < N) ? deg[base + 3] : 0;
    int tsum = v0 + v1 + v2 + v3;
    lds[t] = tsum;
    __syncthreads();
    for (int off = 1; off < 256; off <<= 1) {
        int x = (t >= off) ? lds[t - off] : 0;
        __syncthreads();
        lds[t] += x;
        __syncthreads();
    }
    int excl = lds[t] - tsum;
    if (t == 255) chunk_sums[blockIdx.x] = lds[255];
    int p = excl;
    if (base + 0 < N) rp[base + 0] = p; p += v0;
    if (base + 1 < N) rp[base + 1] = p; p += v1;
    if (base + 2 < N) rp[base + 2] = p; p += v2;
    if (base + 3 < N) rp[base + 3] = p;
}

// ---- exclusive scan, stage 2 (single block, B <= 256) ----
__global__ void scan2_kernel(int* __restrict__ chunk_sums, int B) {
    __shared__ int lds[256];
    int t = threadIdx.x;
    int v = (t < B) ? chunk_sums[t] : 0;
    lds[t] = v;
    __syncthreads();
    for (int off = 1; off < 256; off <<= 1) {
        int x = (t >= off) ? lds[t - off] : 0;
        __syncthreads();
        lds[t] += x;
        __syncthreads();
    }
    if (t < B) chunk_sums[t] = lds[t] - v;  // exclusive
}

// ---- scan stage 3: finalize rp; init cursor; rp[N]=E ----
__global__ void scan3_kernel(int* __restrict__ rp, const int* __restrict__ chunk_sums,
                             int* __restrict__ cursor, int N, int E) {
    int i = blockIdx.x * blockDim.x + threadIdx.x;
    if (i < N) {
        int val = rp[i] + chunk_sums[i >> 10];
        rp[i] = val;
        cursor[i] = val;
    }
    if (i == 0) rp[N] = E;
}

// ---- CSR fill: col[pos] = src[e] ----
__global__ void fill_kernel(const int* __restrict__ src, const int* __restrict__ dst,
                            int* __restrict__ cursor, int* __restrict__ col, int E) {
    int e = blockIdx.x * blockDim.x + threadIdx.x;
    if (e < E) {
        int d = dst[e];
        int pos = atomicAdd(&cursor[d], 1);
        col[pos] = src[e];
    }
}

// ---- init (full path): w0 = half(feats*norm) only ----
__global__ void init_w0_kernel(const float* __restrict__ feats,
                               const float* __restrict__ norm,
                               __half* __restrict__ w, int N) {
    int n = blockIdx.x * (blockDim.x >> 6) + (threadIdx.x >> 6);
    int lane = threadIdx.x & 63;
    if (n >= N) return;
    size_t idx = ((size_t)n << 6) + lane;
    w[idx] = __float2half(feats[idx] * norm[n]);
}

// ---- init (fallback path): out = sigmoid(feats.s)*feats ; w0 = half(feats*norm) ----
__global__ void init_kernel(const float* __restrict__ feats,
                            const float* __restrict__ norm,
                            const float* __restrict__ s,
                            float* __restrict__ out,
                            __half* __restrict__ w, int N) {
    int n = blockIdx.x * (blockDim.x >> 6) + (threadIdx.x >> 6);
    int lane = threadIdx.x & 63;
    if (n >= N) return;
    size_t idx = ((size_t)n << 6) + lane;
    float v = feats[idx];
    float p = v * s[lane];
    #pragma unroll
    for (int off = 32; off; off >>= 1) p += __shfl_xor(p, off, 64);
    float gate = 1.0f / (1.0f + expf(-p));
    out[idx] = gate * v;
    w[idx] = __float2half(v * norm[n]);
}

// ---- hop (full path): wide gather w/ col-preload, UNIFORM-trip shuffle ----
__global__ void gather_hop_store_kernel(const __half* __restrict__ w,
                                        const int* __restrict__ rp,
                                        const int* __restrict__ col,
                                        const float* __restrict__ norm,
                                        __half* __restrict__ wnext, int N) {
    int n = blockIdx.x * (blockDim.x >> 6) + (threadIdx.x >> 6);
    if (n >= N) return;
    int lane  = threadIdx.x & 63;
    int e_sub = lane >> 3;   // edge slot 0..7
    int c     = lane & 7;    // feature chunk 0..7 (8 fp16 = 16B)

    int beg = rp[n];
    int end = rp[n + 1];
    int deg = end - beg;

    // one coalesced load of up to 64 row indices; distribute via shuffle
    int myc = 0;
    if (lane < deg) myc = col[beg + lane];

    float acc[8];
    #pragma unroll
    for (int i = 0; i < 8; ++i) acc[i] = 0.0f;

    int nfull  = (deg < 64) ? deg : 64;
    int ntrips = (nfull + 7) >> 3;          // wave-uniform trip count
    for (int t = 0; t < ntrips; ++t) {
        int jj = e_sub + (t << 3);          // <= 63 always
        // ALL 64 lanes active here -> shuffle sources always valid
        int cc = __shfl(myc, jj, 64);       // cc = 0 for jj >= nfull (myc guard)
        float4 raw = *(const float4*)(w + ((size_t)cc << 6) + (c << 3));
        if (jj < nfull) {                   // mask the accumulate only
            const __half2* h2 = (const __half2*)&raw;
            float2 f0 = __half22float2(h2[0]);
            float2 f1 = __half22float2(h2[1]);
            float2 f2 = __half22float2(h2[2]);
            float2 f3 = __half22float2(h2[3]);
            acc[0] += f0.x; acc[1] += f0.y;
            acc[2] += f1.x; acc[3] += f1.y;
            acc[4] += f2.x; acc[5] += f2.y;
            acc[6] += f3.x; acc[7] += f3.y;
        }
    }
    // tail for deg > 64 (rare; correctness only)
    for (int j = beg + 64 + e_sub; j < end; j += 8) {
        int cc = col[j];
        float4 raw = *(const float4*)(w + ((size_t)cc << 6) + (c << 3));
        const __half2* h2 = (const __half2*)&raw;
        float2 f0 = __half22float2(h2[0]);
        float2 f1 = __half22float2(h2[1]);
        float2 f2 = __half22float2(h2[2]);
        float2 f3 = __half22float2(h2[3]);
        acc[0] += f0.x; acc[1] += f0.y;
        acc[2] += f1.x; acc[3] += f1.y;
        acc[4] += f2.x; acc[5] += f2.y;
        acc[6] += f3.x; acc[7] += f3.y;
    }

    // fold edge slots (lane bits 3..5) — all lanes reconverged
    #pragma unroll
    for (int off = 8; off < 64; off <<= 1) {
        #pragma unroll
        for (int i = 0; i < 8; ++i) acc[i] += __shfl_xor(acc[i], off, 64);
    }

    if (e_sub == 0) {
        float nm = norm[n];
        float n2 = nm * nm;
        __half2 hv[4];
        hv[0] = __floats2half2_rn(acc[0] * n2, acc[1] * n2);
        hv[1] = __floats2half2_rn(acc[2] * n2, acc[3] * n2);
        hv[2] = __floats2half2_rn(acc[4] * n2, acc[5] * n2);
        hv[3] = __floats2half2_rn(acc[6] * n2, acc[7] * n2);
        *(float4*)(wnext + ((size_t)n << 6) + (c << 3)) = *(const float4*)hv;
    }
}

// ---- wide readout: lanes = (k-slot e_sub x chunk c); 16B loads ----
// out[n] = sum_k sigmoid(h_k.s) * h_k, where h_k = w_k / norm[n]
__global__ void readout_kernel(const __half* __restrict__ wbase,  // w_0
                               const float* __restrict__ norm,
                               const float* __restrict__ s,
                               float* __restrict__ out,
                               int N, int nk, size_t kstride) {
    int n = blockIdx.x * (blockDim.x >> 6) + (threadIdx.x >> 6);
    if (n >= N) return;
    int lane  = threadIdx.x & 63;
    int e_sub = lane >> 3;   // k slot 0..7
    int c     = lane & 7;    // feature chunk

    float4 sa = *(const float4*)(s + (c << 3));
    float4 sb = *(const float4*)(s + (c << 3) + 4);

    float inm = 1.0f / norm[n];   // = sqrt(deg)
    size_t rowbase = ((size_t)n << 6) + (c << 3);

    float acc[8];
    #pragma unroll
    for (int i = 0; i < 8; ++i) acc[i] = 0.0f;

    #pragma unroll
    for (int iter = 0; iter < 2; ++iter) {
        int k = e_sub + iter * 8;
        float h[8];
        if (k < nk) {
            float4 raw = *(const float4*)(wbase + rowbase + (size_t)k * kstride);
            const __half2* h2 = (const __half2*)&raw;
            float2 f0 = __half22float2(h2[0]);
            float2 f1 = __half22float2(h2[1]);
            float2 f2 = __half22float2(h2[2]);
            float2 f3 = __half22float2(h2[3]);
            h[0] = f0.x * inm; h[1] = f0.y * inm;
            h[2] = f1.x * inm; h[3] = f1.y * inm;
            h[4] = f2.x * inm; h[5] = f2.y * inm;
            h[6] = f3.x * inm; h[7] = f3.y * inm;
        } else {
            #pragma unroll
            for (int i = 0; i < 8; ++i) h[i] = 0.0f;
        }
        // gate dot: partial over own chunk, reduce over c (lane bits 0..2)
        // (all lanes reconverged before the shuffle)
        float p = h[0] * sa.x + h[1] * sa.y + h[2] * sa.z + h[3] * sa.w
                + h[4] * sb.x + h[5] * sb.y + h[6] * sb.z + h[7] * sb.w;
        #pragma unroll
        for (int off = 1; off < 8; off <<= 1) p += __shfl_xor(p, off, 64);
        float gate = 1.0f / (1.0f + expf(-p));
        #pragma unroll
        for (int i = 0; i < 8; ++i) acc[i] += gate * h[i];
    }

    // fold k slots (lane bits 3..5)
    #pragma unroll
    for (int off = 8; off < 64; off <<= 1) {
        #pragma unroll
        for (int i = 0; i < 8; ++i) acc[i] += __shfl_xor(acc[i], off, 64);
    }

    if (e_sub == 0) {
        float4 o0 = make_float4(acc[0], acc[1], acc[2], acc[3]);
        float4 o1 = make_float4(acc[4], acc[5], acc[6], acc[7]);
        float4* o = (float4*)(out + rowbase);
        o[0] = o0; o[1] = o1;
    }
}

// ---- hop (fallback path): gather + gate + out RMW + next-state ----
__global__ void gather_hop_kernel(const __half* __restrict__ w,
                                  const int* __restrict__ rp,
                                  const int* __restrict__ col,
                                  const float* __restrict__ norm,
                                  const float* __restrict__ s,
                                  float* __restrict__ out,
                                  __half* __restrict__ wnext,
                                  int N, int write_next) {
    int n = blockIdx.x * (blockDim.x >> 6) + (threadIdx.x >> 6);
    if (n >= N) return;
    int lane = threadIdx.x & 63;
    int e_sub = lane >> 3;
    int c     = lane & 7;

    int beg = rp[n];
    int end = rp[n + 1];

    float acc[8];
    #pragma unroll
    for (int i = 0; i < 8; ++i) acc[i] = 0.0f;

    for (int j = beg + e_sub; j < end; j += 8) {
        int cc = col[j];
        float4 raw = *(const float4*)(w + ((size_t)cc << 6) + (c << 3));
        const __half2* h2 = (const __half2*)&raw;
        float2 f0 = __half22float2(h2[0]);
        float2 f1 = __half22float2(h2[1]);
        float2 f2 = __half22float2(h2[2]);
        float2 f3 = __half22float2(h2[3]);
        acc[0] += f0.x; acc[1] += f0.y;
        acc[2] += f1.x; acc[3] += f1.y;
        acc[4] += f2.x; acc[5] += f2.y;
        acc[6] += f3.x; acc[7] += f3.y;
    }

    #pragma unroll
    for (int off = 8; off < 64; off <<= 1) {
        #pragma unroll
        for (int i = 0; i < 8; ++i) acc[i] += __shfl_xor(acc[i], off, 64);
    }

    float nm = norm[n];
    float v[8];
    #pragma unroll
    for (int i = 0; i < 8; ++i) v[i] = acc[i] * nm;

    float4 sa = *(const float4*)(s + (c << 3));
    float4 sb = *(const float4*)(s + (c << 3) + 4);
    float p = v[0] * sa.x + v[1] * sa.y + v[2] * sa.z + v[3] * sa.w
            + v[4] * sb.x + v[5] * sb.y + v[6] * sb.z + v[7] * sb.w;
    #pragma unroll
    for (int off = 1; off < 8; off <<= 1) p += __shfl_xor(p, off, 64);
    float gate = 1.0f / (1.0f + expf(-p));

    size_t base = ((size_t)n << 6) + (c << 3);
    if (e_sub == 0) {
        float4* o = (float4*)(out + base);
        float4 o0 = o[0], o1 = o[1];
        o0.x += gate * v[0]; o0.y += gate * v[1];
        o0.z += gate * v[2]; o0.w += gate * v[3];
        o1.x += gate * v[4]; o1.y += gate * v[5];
        o1.z += gate * v[6]; o1.w += gate * v[7];
        o[0] = o0; o[1] = o1;
    } else if (e_sub == 1 && write_next) {
        __half2 hv[4];
        hv[0] = __floats2half2_rn(v[0] * nm, v[1] * nm);
        hv[1] = __floats2half2_rn(v[2] * nm, v[3] * nm);
        hv[2] = __floats2half2_rn(v[4] * nm, v[5] * nm);
        hv[3] = __floats2half2_rn(v[6] * nm, v[7] * nm);
        *(float4*)(wnext + base) = *(const float4*)hv;
    }
}

extern "C" void kernel_launch(void* const* d_in, const int* in_sizes, int n_in,
                              void* d_out, int out_size, void* d_ws, size_t ws_size,
                              hipStream_t stream) {
    const float* feats = (const float*)d_in[0];
    const float* s     = (const float*)d_in[1];
    const int*   src   = (const int*)d_in[2];
    const int*   dst   = (const int*)d_in[3];
    float* out = (float*)d_out;

    const int N = in_sizes[0] / DIM;
    const int E = in_sizes[2];
    const int K = 10;

    const int BLK = 256;
    const int wavesPerBlk = BLK / 64;
    const int chunks = (N + 1023) / 1024;   // must be <= 256
    int nodeBlocks = (N + wavesPerBlk - 1) / wavesPerBlk;
    int intCount = (N + 1) + N + N + E + 256;   // rp, deg, cursor, col, chunk

    size_t stateElems = (size_t)N * DIM;
    size_t need_full = (size_t)N * 4 + (size_t)(K + 1) * stateElems * 2
                     + (size_t)intCount * 4 + 64;
    int full = (ws_size >= need_full) ? 1 : 0;
    int nbuf = full ? (K + 1) : 2;

    float*  norm  = (float*)d_ws;
    __half* wbase = (__half*)(norm + N);
    int*    rp     = (int*)(wbase + (size_t)nbuf * stateElems);
    int*    deg    = rp + (N + 1);
    int*    cursor = deg + N;
    int*    col    = cursor + N;
    int*    chunk  = col + E;

    zero_int_kernel<<<(N + BLK - 1) / BLK, BLK, 0, stream>>>(deg, N);
    degree_kernel<<<(E + BLK - 1) / BLK, BLK, 0, stream>>>(dst, deg, E);
    norm_kernel<<<(N + BLK - 1) / BLK, BLK, 0, stream>>>(deg, norm, N);

    scan1_kernel<<<chunks, 256, 0, stream>>>(deg, rp, chunk, N);
    scan2_kernel<<<1, 256, 0, stream>>>(chunk, chunks);
    scan3_kernel<<<(N + BLK - 1) / BLK, BLK, 0, stream>>>(rp, chunk, cursor, N, E);
    fill_kernel<<<(E + BLK - 1) / BLK, BLK, 0, stream>>>(src, dst, cursor, col, E);

    if (full) {
        init_w0_kernel<<<nodeBlocks, BLK, 0, stream>>>(feats, norm, wbase, N);
        for (int k = 0; k < K; ++k) {
            const __half* cur = wbase + (size_t)k * stateElems;
            __half* nxt = wbase + (size_t)(k + 1) * stateElems;
            gather_hop_store_kernel<<<nodeBlocks, BLK, 0, stream>>>(cur, rp, col,
                                                                    norm, nxt, N);
        }
        readout_kernel<<<nodeBlocks, BLK, 0, stream>>>(wbase, norm, s, out,
                                                       N, K + 1, stateElems);
    } else {
        __half* wA = wbase;
        __half* wB = wbase + stateElems;
        init_kernel<<<nodeBlocks, BLK, 0, stream>>>(feats, norm, s, out, wA, N);
        __half* cur = wA;
        __half* nxt = wB;
        for (int k = 0; k < K; ++k) {
            int write_next = (k < K - 1) ? 1 : 0;
            gather_hop_kernel<<<nodeBlocks, BLK, 0, stream>>>(cur, rp, col, norm, s,
                                                              out, nxt, N, write_next);
            __half* t = cur; cur = nxt; nxt = t;
        }
    }
}

// Round 10
// 579.980 us; speedup vs baseline: 1.5719x; 1.1022x over previous
//
#include <hip/hip_runtime.h>
#include <hip/hip_bf16.h>
#include <hip/hip_fp16.h>
#include <math.h>

// DAGNN propagation, CSR-gather, fp16 state, wide gather (8 edges/wave-instr).
// Round 10: XCD-partitioned degree + CSR fill (partition p = blockIdx%8 handles
// dst range p -> writes are single-XCD, L2-resident, no cross-XCD line
// ping-pong); hop kernel issues the first two gather trips unconditionally.

#define DIM 64
#define NPART 8          // matches 8 XCDs; blockIdx%8 ~ XCD round-robin heuristic

// ---- zero int region ----
__global__ void zero_int_kernel(int* __restrict__ p, int n) {
    int i = blockIdx.x * blockDim.x + threadIdx.x;
    if (i < n) p[i] = 0;
}

// ---- partitioned in-degree: partition p counts only dst in its node range ----
__global__ void degree_part_kernel(const int* __restrict__ dst, int* __restrict__ deg,
                                   int E, int loN_per, int N) {
    int p   = blockIdx.x & (NPART - 1);
    int sub = blockIdx.x >> 3;
    int nsub = gridDim.x >> 3;
    int lo = p * loN_per;
    int hi = lo + loN_per; if (hi > N) hi = N;
    for (int e = sub * blockDim.x + threadIdx.x; e < E; e += nsub * blockDim.x) {
        int d = dst[e];
        if (d >= lo && d < hi) atomicAdd(&deg[d], 1);
    }
}

// ---- norm = deg^-0.5 ----
__global__ void norm_kernel(const int* __restrict__ deg, float* __restrict__ norm, int N) {
    int i = blockIdx.x * blockDim.x + threadIdx.x;
    if (i < N) norm[i] = rsqrtf((float)deg[i]);
}

// ---- exclusive scan, stage 1: per-1024-chunk scan + chunk totals ----
__global__ void scan1_kernel(const int* __restrict__ deg, int* __restrict__ rp,
                             int* __restrict__ chunk_sums, int N) {
    __shared__ int lds[256];
    int t = threadIdx.x;
    int base = blockIdx.x * 1024 + t * 4;
    int v0 = (base + 0 < N) ? deg[base + 0] : 0;
    int v1 = (base + 1 < N) ? deg[base + 1] : 0;
    int v2 = (base + 2 < N) ? deg[base + 2] : 0;
    int v3 = (base + 3 < N) ? deg[base + 3] : 0;
    int tsum = v0 + v1 + v2 + v3;
    lds[t] = tsum;
    __syncthreads();
    for (int off = 1; off < 256; off <<= 1) {
        int x = (t >= off) ? lds[t - off] : 0;
        __syncthreads();
        lds[t] += x;
        __syncthreads();
    }
    int excl = lds[t] - tsum;
    if (t == 255) chunk_sums[blockIdx.x] = lds[255];
    int p = excl;
    if (base + 0 < N) rp[base + 0] = p; p += v0;
    if (base + 1 < N) rp[base + 1] = p; p += v1;
    if (base + 2 < N) rp[base + 2] = p; p += v2;
    if (base + 3 < N) rp[base + 3] = p;
}

// ---- exclusive scan, stage 2 (single block, B <= 256) ----
__global__ void scan2_kernel(int* __restrict__ chunk_sums, int B) {
    __shared__ int lds[256];
    int t = threadIdx.x;
    int v = (t < B) ? chunk_sums[t] : 0;
    lds[t] = v;
    __syncthreads();
    for (int off = 1; off < 256; off <<= 1) {
        int x = (t >= off) ? lds[t - off] : 0;
        __syncthreads();
        lds[t] += x;
        __syncthreads();
    }
    if (t < B) chunk_sums[t] = lds[t] - v;  // exclusive
}

// ---- scan stage 3: finalize rp; init cursor; rp[N]=E ----
__global__ void scan3_kernel(int* __restrict__ rp, const int* __restrict__ chunk_sums,
                             int* __restrict__ cursor, int N, int E) {
    int i = blockIdx.x * blockDim.x + threadIdx.x;
    if (i < N) {
        int val = rp[i] + chunk_sums[i >> 10];
        rp[i] = val;
        cursor[i] = val;
    }
    if (i == 0) rp[N] = E;
}

// ---- partitioned CSR fill: partition p fills only its dst range ----
// col region per partition (~E/8 ints) has a single-XCD writer -> lines fill
// completely in that XCD's L2 -> ~1x write amplification (vs 16x global).
__global__ void fill_part_kernel(const int* __restrict__ src, const int* __restrict__ dst,
                                 int* __restrict__ cursor, int* __restrict__ col,
                                 int E, int loN_per, int N) {
    int p   = blockIdx.x & (NPART - 1);
    int sub = blockIdx.x >> 3;
    int nsub = gridDim.x >> 3;
    int lo = p * loN_per;
    int hi = lo + loN_per; if (hi > N) hi = N;
    for (int e = sub * blockDim.x + threadIdx.x; e < E; e += nsub * blockDim.x) {
        int d = dst[e];
        if (d >= lo && d < hi) {
            int pos = atomicAdd(&cursor[d], 1);
            col[pos] = src[e];
        }
    }
}

// ---- init: w0 = half(feats*norm) ----
__global__ void init_w0_kernel(const float* __restrict__ feats,
                               const float* __restrict__ norm,
                               __half* __restrict__ w, int N) {
    int n = blockIdx.x * (blockDim.x >> 6) + (threadIdx.x >> 6);
    int lane = threadIdx.x & 63;
    if (n >= N) return;
    size_t idx = ((size_t)n << 6) + lane;
    w[idx] = __float2half(feats[idx] * norm[n]);
}

// ---- hop: wide gather w/ col-preload, uniform-trip shuffle, 2-trip fast path ----
__global__ void gather_hop_store_kernel(const __half* __restrict__ w,
                                        const int* __restrict__ rp,
                                        const int* __restrict__ col,
                                        const float* __restrict__ norm,
                                        __half* __restrict__ wnext, int N) {
    int n = blockIdx.x * (blockDim.x >> 6) + (threadIdx.x >> 6);
    if (n >= N) return;
    int lane  = threadIdx.x & 63;
    int e_sub = lane >> 3;   // edge slot 0..7
    int c     = lane & 7;    // feature chunk 0..7 (8 fp16 = 16B)

    int beg = rp[n];
    int end = rp[n + 1];
    int deg = end - beg;
    float nm = norm[n];      // hoisted: overlaps with gathers

    // one coalesced load of up to 64 row indices; distribute via shuffle
    int myc = 0;
    if (lane < deg) myc = col[beg + lane];

    float acc[8];
    #pragma unroll
    for (int i = 0; i < 8; ++i) acc[i] = 0.0f;

    int nfull = (deg < 64) ? deg : 64;

    // fast path: first two trips unconditional (covers deg <= 16, ~84% of nodes);
    // both loads issue back-to-back, masked accumulate. All 64 lanes active at
    // every __shfl (sources valid; myc=0 guard for jj >= deg).
    {
        int cc0 = __shfl(myc, e_sub, 64);
        int cc1 = __shfl(myc, e_sub + 8, 64);
        float4 raw0 = *(const float4*)(w + ((size_t)cc0 << 6) + (c << 3));
        float4 raw1 = *(const float4*)(w + ((size_t)cc1 << 6) + (c << 3));
        if (e_sub < nfull) {
            const __half2* h2 = (const __half2*)&raw0;
            float2 f0 = __half22float2(h2[0]);
            float2 f1 = __half22float2(h2[1]);
            float2 f2 = __half22float2(h2[2]);
            float2 f3 = __half22float2(h2[3]);
            acc[0] += f0.x; acc[1] += f0.y;
            acc[2] += f1.x; acc[3] += f1.y;
            acc[4] += f2.x; acc[5] += f2.y;
            acc[6] += f3.x; acc[7] += f3.y;
        }
        if (e_sub + 8 < nfull) {
            const __half2* h2 = (const __half2*)&raw1;
            float2 f0 = __half22float2(h2[0]);
            float2 f1 = __half22float2(h2[1]);
            float2 f2 = __half22float2(h2[2]);
            float2 f3 = __half22float2(h2[3]);
            acc[0] += f0.x; acc[1] += f0.y;
            acc[2] += f1.x; acc[3] += f1.y;
            acc[4] += f2.x; acc[5] += f2.y;
            acc[6] += f3.x; acc[7] += f3.y;
        }
    }
    // remaining trips (deg > 16), wave-uniform trip count
    int ntrips = (nfull + 7) >> 3;
    for (int t = 2; t < ntrips; ++t) {
        int jj = e_sub + (t << 3);          // <= 63 always
        int cc = __shfl(myc, jj, 64);
        float4 raw = *(const float4*)(w + ((size_t)cc << 6) + (c << 3));
        if (jj < nfull) {
            const __half2* h2 = (const __half2*)&raw;
            float2 f0 = __half22float2(h2[0]);
            float2 f1 = __half22float2(h2[1]);
            float2 f2 = __half22float2(h2[2]);
            float2 f3 = __half22float2(h2[3]);
            acc[0] += f0.x; acc[1] += f0.y;
            acc[2] += f1.x; acc[3] += f1.y;
            acc[4] += f2.x; acc[5] += f2.y;
            acc[6] += f3.x; acc[7] += f3.y;
        }
    }
    // tail for deg > 64 (rare; correctness only)
    for (int j = beg + 64 + e_sub; j < end; j += 8) {
        int cc = col[j];
        float4 raw = *(const float4*)(w + ((size_t)cc << 6) + (c << 3));
        const __half2* h2 = (const __half2*)&raw;
        float2 f0 = __half22float2(h2[0]);
        float2 f1 = __half22float2(h2[1]);
        float2 f2 = __half22float2(h2[2]);
        float2 f3 = __half22float2(h2[3]);
        acc[0] += f0.x; acc[1] += f0.y;
        acc[2] += f1.x; acc[3] += f1.y;
        acc[4] += f2.x; acc[5] += f2.y;
        acc[6] += f3.x; acc[7] += f3.y;
    }

    // fold edge slots (lane bits 3..5) — all lanes reconverged
    #pragma unroll
    for (int off = 8; off < 64; off <<= 1) {
        #pragma unroll
        for (int i = 0; i < 8; ++i) acc[i] += __shfl_xor(acc[i], off, 64);
    }

    if (e_sub == 0) {
        float n2 = nm * nm;
        __half2 hv[4];
        hv[0] = __floats2half2_rn(acc[0] * n2, acc[1] * n2);
        hv[1] = __floats2half2_rn(acc[2] * n2, acc[3] * n2);
        hv[2] = __floats2half2_rn(acc[4] * n2, acc[5] * n2);
        hv[3] = __floats2half2_rn(acc[6] * n2, acc[7] * n2);
        *(float4*)(wnext + ((size_t)n << 6) + (c << 3)) = *(const float4*)hv;
    }
}

// ---- wide readout: lanes = (k-slot e_sub x chunk c); 16B loads ----
__global__ void readout_kernel(const __half* __restrict__ wbase,  // w_0
                               const float* __restrict__ norm,
                               const float* __restrict__ s,
                               float* __restrict__ out,
                               int N, int nk, size_t kstride) {
    int n = blockIdx.x * (blockDim.x >> 6) + (threadIdx.x >> 6);
    if (n >= N) return;
    int lane  = threadIdx.x & 63;
    int e_sub = lane >> 3;   // k slot 0..7
    int c     = lane & 7;    // feature chunk

    float4 sa = *(const float4*)(s + (c << 3));
    float4 sb = *(const float4*)(s + (c << 3) + 4);

    float inm = 1.0f / norm[n];   // = sqrt(deg)
    size_t rowbase = ((size_t)n << 6) + (c << 3);

    float acc[8];
    #pragma unroll
    for (int i = 0; i < 8; ++i) acc[i] = 0.0f;

    #pragma unroll
    for (int iter = 0; iter < 2; ++iter) {
        int k = e_sub + iter * 8;
        float h[8];
        if (k < nk) {
            float4 raw = *(const float4*)(wbase + rowbase + (size_t)k * kstride);
            const __half2* h2 = (const __half2*)&raw;
            float2 f0 = __half22float2(h2[0]);
            float2 f1 = __half22float2(h2[1]);
            float2 f2 = __half22float2(h2[2]);
            float2 f3 = __half22float2(h2[3]);
            h[0] = f0.x * inm; h[1] = f0.y * inm;
            h[2] = f1.x * inm; h[3] = f1.y * inm;
            h[4] = f2.x * inm; h[5] = f2.y * inm;
            h[6] = f3.x * inm; h[7] = f3.y * inm;
        } else {
            #pragma unroll
            for (int i = 0; i < 8; ++i) h[i] = 0.0f;
        }
        float p = h[0] * sa.x + h[1] * sa.y + h[2] * sa.z + h[3] * sa.w
                + h[4] * sb.x + h[5] * sb.y + h[6] * sb.z + h[7] * sb.w;
        #pragma unroll
        for (int off = 1; off < 8; off <<= 1) p += __shfl_xor(p, off, 64);
        float gate = 1.0f / (1.0f + expf(-p));
        #pragma unroll
        for (int i = 0; i < 8; ++i) acc[i] += gate * h[i];
    }

    // fold k slots (lane bits 3..5)
    #pragma unroll
    for (int off = 8; off < 64; off <<= 1) {
        #pragma unroll
        for (int i = 0; i < 8; ++i) acc[i] += __shfl_xor(acc[i], off, 64);
    }

    if (e_sub == 0) {
        float4 o0 = make_float4(acc[0], acc[1], acc[2], acc[3]);
        float4 o1 = make_float4(acc[4], acc[5], acc[6], acc[7]);
        float4* o = (float4*)(out + rowbase);
        o[0] = o0; o[1] = o1;
    }
}

// ---- fallback (small ws): fused hop with out RMW ----
__global__ void init_kernel(const float* __restrict__ feats,
                            const float* __restrict__ norm,
                            const float* __restrict__ s,
                            float* __restrict__ out,
                            __half* __restrict__ w, int N) {
    int n = blockIdx.x * (blockDim.x >> 6) + (threadIdx.x >> 6);
    int lane = threadIdx.x & 63;
    if (n >= N) return;
    size_t idx = ((size_t)n << 6) + lane;
    float v = feats[idx];
    float p = v * s[lane];
    #pragma unroll
    for (int off = 32; off; off >>= 1) p += __shfl_xor(p, off, 64);
    float gate = 1.0f / (1.0f + expf(-p));
    out[idx] = gate * v;
    w[idx] = __float2half(v * norm[n]);
}

__global__ void gather_hop_kernel(const __half* __restrict__ w,
                                  const int* __restrict__ rp,
                                  const int* __restrict__ col,
                                  const float* __restrict__ norm,
                                  const float* __restrict__ s,
                                  float* __restrict__ out,
                                  __half* __restrict__ wnext,
                                  int N, int write_next) {
    int n = blockIdx.x * (blockDim.x >> 6) + (threadIdx.x >> 6);
    if (n >= N) return;
    int lane = threadIdx.x & 63;
    int e_sub = lane >> 3;
    int c     = lane & 7;

    int beg = rp[n];
    int end = rp[n + 1];

    float acc[8];
    #pragma unroll
    for (int i = 0; i < 8; ++i) acc[i] = 0.0f;

    for (int j = beg + e_sub; j < end; j += 8) {
        int cc = col[j];
        float4 raw = *(const float4*)(w + ((size_t)cc << 6) + (c << 3));
        const __half2* h2 = (const __half2*)&raw;
        float2 f0 = __half22float2(h2[0]);
        float2 f1 = __half22float2(h2[1]);
        float2 f2 = __half22float2(h2[2]);
        float2 f3 = __half22float2(h2[3]);
        acc[0] += f0.x; acc[1] += f0.y;
        acc[2] += f1.x; acc[3] += f1.y;
        acc[4] += f2.x; acc[5] += f2.y;
        acc[6] += f3.x; acc[7] += f3.y;
    }

    #pragma unroll
    for (int off = 8; off < 64; off <<= 1) {
        #pragma unroll
        for (int i = 0; i < 8; ++i) acc[i] += __shfl_xor(acc[i], off, 64);
    }

    float nm = norm[n];
    float v[8];
    #pragma unroll
    for (int i = 0; i < 8; ++i) v[i] = acc[i] * nm;

    float4 sa = *(const float4*)(s + (c << 3));
    float4 sb = *(const float4*)(s + (c << 3) + 4);
    float p = v[0] * sa.x + v[1] * sa.y + v[2] * sa.z + v[3] * sa.w
            + v[4] * sb.x + v[5] * sb.y + v[6] * sb.z + v[7] * sb.w;
    #pragma unroll
    for (int off = 1; off < 8; off <<= 1) p += __shfl_xor(p, off, 64);
    float gate = 1.0f / (1.0f + expf(-p));

    size_t base = ((size_t)n << 6) + (c << 3);
    if (e_sub == 0) {
        float4* o = (float4*)(out + base);
        float4 o0 = o[0], o1 = o[1];
        o0.x += gate * v[0]; o0.y += gate * v[1];
        o0.z += gate * v[2]; o0.w += gate * v[3];
        o1.x += gate * v[4]; o1.y += gate * v[5];
        o1.z += gate * v[6]; o1.w += gate * v[7];
        o[0] = o0; o[1] = o1;
    } else if (e_sub == 1 && write_next) {
        __half2 hv[4];
        hv[0] = __floats2half2_rn(v[0] * nm, v[1] * nm);
        hv[1] = __floats2half2_rn(v[2] * nm, v[3] * nm);
        hv[2] = __floats2half2_rn(v[4] * nm, v[5] * nm);
        hv[3] = __floats2half2_rn(v[6] * nm, v[7] * nm);
        *(float4*)(wnext + base) = *(const float4*)hv;
    }
}

extern "C" void kernel_launch(void* const* d_in, const int* in_sizes, int n_in,
                              void* d_out, int out_size, void* d_ws, size_t ws_size,
                              hipStream_t stream) {
    const float* feats = (const float*)d_in[0];
    const float* s     = (const float*)d_in[1];
    const int*   src   = (const int*)d_in[2];
    const int*   dst   = (const int*)d_in[3];
    float* out = (float*)d_out;

    const int N = in_sizes[0] / DIM;
    const int E = in_sizes[2];
    const int K = 10;

    const int BLK = 256;
    const int wavesPerBlk = BLK / 64;
    const int chunks = (N + 1023) / 1024;   // must be <= 256
    int nodeBlocks = (N + wavesPerBlk - 1) / wavesPerBlk;
    int intCount = (N + 1) + N + N + E + 256;   // rp, deg, cursor, col, chunk
    int nodesPerPart = (N + NPART - 1) / NPART;
    const int PART_BLOCKS = 2048;               // 256 blocks per partition

    size_t stateElems = (size_t)N * DIM;
    size_t need_full = (size_t)N * 4 + (size_t)(K + 1) * stateElems * 2
                     + (size_t)intCount * 4 + 64;
    int full = (ws_size >= need_full) ? 1 : 0;
    int nbuf = full ? (K + 1) : 2;

    float*  norm  = (float*)d_ws;
    __half* wbase = (__half*)(norm + N);
    int*    rp     = (int*)(wbase + (size_t)nbuf * stateElems);
    int*    deg    = rp + (N + 1);
    int*    cursor = deg + N;
    int*    col    = cursor + N;
    int*    chunk  = col + E;

    zero_int_kernel<<<(N + BLK - 1) / BLK, BLK, 0, stream>>>(deg, N);
    degree_part_kernel<<<PART_BLOCKS, BLK, 0, stream>>>(dst, deg, E, nodesPerPart, N);
    norm_kernel<<<(N + BLK - 1) / BLK, BLK, 0, stream>>>(deg, norm, N);

    scan1_kernel<<<chunks, 256, 0, stream>>>(deg, rp, chunk, N);
    scan2_kernel<<<1, 256, 0, stream>>>(chunk, chunks);
    scan3_kernel<<<(N + BLK - 1) / BLK, BLK, 0, stream>>>(rp, chunk, cursor, N, E);
    fill_part_kernel<<<PART_BLOCKS, BLK, 0, stream>>>(src, dst, cursor, col,
                                                      E, nodesPerPart, N);

    if (full) {
        init_w0_kernel<<<nodeBlocks, BLK, 0, stream>>>(feats, norm, wbase, N);
        for (int k = 0; k < K; ++k) {
            const __half* cur = wbase + (size_t)k * stateElems;
            __half* nxt = wbase + (size_t)(k + 1) * stateElems;
            gather_hop_store_kernel<<<nodeBlocks, BLK, 0, stream>>>(cur, rp, col,
                                                                    norm, nxt, N);
        }
        readout_kernel<<<nodeBlocks, BLK, 0, stream>>>(wbase, norm, s, out,
                                                       N, K + 1, stateElems);
    } else {
        __half* wA = wbase;
        __half* wB = wbase + stateElems;
        init_kernel<<<nodeBlocks, BLK, 0, stream>>>(feats, norm, s, out, wA, N);
        __half* cur = wA;
        __half* nxt = wB;
        for (int k = 0; k < K; ++k) {
            int write_next = (k < K - 1) ? 1 : 0;
            gather_hop_kernel<<<nodeBlocks, BLK, 0, stream>>>(cur, rp, col, norm, s,
                                                              out, nxt, N, write_next);
            __half* t = cur; cur = nxt; nxt = t;
        }
    }
}